// Round 4
// baseline (1964.596 us; speedup 1.0000x reference)
//
#include <hip/hip_runtime.h>

#define D 300
#define KP 320
#define NPAD 50048
#define NT64 782        // NPAD/64 row-tiles of 64
#define NGR 256
#define NL 5
#define NC 128
#define BN_EPS 1e-5f

typedef __attribute__((ext_vector_type(8))) short bf16x8;
typedef __attribute__((ext_vector_type(4))) float f32x4;
typedef unsigned short u16;

__device__ __forceinline__ void atomAdd(float* p, float v) { unsafeAtomicAdd(p, v); }

__device__ __forceinline__ short f2bf(float f) {
    union { float f; unsigned u; } v; v.f = f;
    unsigned r = v.u + 0x7fffu + ((v.u >> 16) & 1u);   // RNE
    return (short)(r >> 16);
}
__device__ __forceinline__ float bf2f(short s) {
    union { unsigned u; float f; } v;
    v.u = ((unsigned)(u16)s) << 16;
    return v.f;
}
// HW packed f32->bf16 (RNE), 1 instr per 2 values
__device__ __forceinline__ unsigned cvtpk(float lo, float hi) {
    unsigned r;
    asm("v_cvt_pk_bf16_f32 %0, %1, %2" : "=v"(r) : "v"(lo), "v"(hi));
    return r;
}
// DPP row_shr reduce over a 16-lane row: lane with (lane&15)==15 holds the sum.
template<int C>
__device__ __forceinline__ float rs_add(float v) {
    int x = __builtin_amdgcn_update_dpp(0, __float_as_int(v), C, 0xF, 0xF, true);
    return v + __int_as_float(x);
}
__device__ __forceinline__ float red16(float v) {
    v = rs_add<0x111>(v);   // row_shr:1
    v = rs_add<0x112>(v);   // row_shr:2
    v = rs_add<0x114>(v);   // row_shr:4
    v = rs_add<0x118>(v);   // row_shr:8
    return v;
}
// async global->LDS, 16B per lane; LDS dest lane-linear, global src per-lane
__device__ __forceinline__ void gload_lds16(const u16* g, u16* l) {
    __builtin_amdgcn_global_load_lds((const __attribute__((address_space(1))) void*)g,
                                     (__attribute__((address_space(3))) void*)l, 16, 0, 0);
}

// ---------------------------------------------------------------------------
// offsets: off[g] = lower_bound(batch, g)
// ---------------------------------------------------------------------------
__global__ void offsets_kernel(const int* __restrict__ batch, int* __restrict__ off, int N) {
    int g = threadIdx.x;
    if (g > NGR) return;
    int lo = 0, hi = N;
    while (lo < hi) {
        int mid = (lo + hi) >> 1;
        if (batch[mid] < g) lo = mid + 1; else hi = mid;
    }
    off[g] = lo;
}

// ---------------------------------------------------------------------------
// CSR build: deg histogram -> hierarchical scan -> slot fill
// ---------------------------------------------------------------------------
__global__ __launch_bounds__(256)
void deg_kernel(const int* __restrict__ ei, int* __restrict__ deg, int E) {
    int e = blockIdx.x * 256 + threadIdx.x;
    if (e < E) atomicAdd(&deg[ei[E + e]], 1);
}

__global__ __launch_bounds__(256)
void degpart_kernel(const int* __restrict__ deg, int* __restrict__ part, int N) {
    int i = blockIdx.x * 256 + threadIdx.x;
    int v = (i < N) ? deg[i] : 0;
    #pragma unroll
    for (int o = 1; o < 64; o <<= 1) v += __shfl_xor(v, o);
    __shared__ int ws[4];
    if ((threadIdx.x & 63) == 0) ws[threadIdx.x >> 6] = v;
    __syncthreads();
    if (threadIdx.x == 0) part[blockIdx.x] = ws[0] + ws[1] + ws[2] + ws[3];
}

__global__ __launch_bounds__(256)
void partscan_kernel(int* __restrict__ part, int nb) {   // 1 block; nb <= 256
    __shared__ int buf[256];
    int t = threadIdx.x;
    int v = (t < nb) ? part[t] : 0;
    buf[t] = v;
    __syncthreads();
    for (int o = 1; o < 256; o <<= 1) {
        int u = (t >= o) ? buf[t - o] : 0;
        __syncthreads();
        buf[t] += u;
        __syncthreads();
    }
    if (t < nb) part[t] = (t == 0) ? 0 : buf[t - 1];   // exclusive
}

__global__ __launch_bounds__(256)
void rowptr_kernel(const int* __restrict__ deg, const int* __restrict__ part,
                   int* __restrict__ rowptr, int N, int E) {
    __shared__ int buf[256];
    int b = blockIdx.x, t = threadIdx.x;
    int i = b * 256 + t;
    int v = (i < N) ? deg[i] : 0;
    buf[t] = v;
    __syncthreads();
    for (int o = 1; o < 256; o <<= 1) {
        int u = (t >= o) ? buf[t - o] : 0;
        __syncthreads();
        buf[t] += u;
        __syncthreads();
    }
    if (i < N) rowptr[i] = part[b] + buf[t] - v;
    if (b == 0 && t == 0) rowptr[N] = E;
}

__global__ __launch_bounds__(256)
void fill_kernel(const int* __restrict__ ei, const int* __restrict__ rowptr,
                 int* __restrict__ cursor, int* __restrict__ col, int E) {
    int e = blockIdx.x * 256 + threadIdx.x;
    if (e >= E) return;
    int src = ei[e];
    int dst = ei[E + e];
    int pos = atomicAdd(&cursor[dst], 1);
    col[rowptr[dst] + pos] = src;
}

// ---------------------------------------------------------------------------
// weight convert: Wt[mat][n (320)][k (320)] = bf16(W[k][n]); pads zero
// ---------------------------------------------------------------------------
__global__ __launch_bounds__(256)
void wcvt_kernel(const float* __restrict__ W1, const float* __restrict__ W2,
                 u16* __restrict__ Wt) {
    int idx = blockIdx.x * 256 + threadIdx.x;
    if (idx >= 10 * KP * 80) return;
    int n4 = idx % 80;
    int k = (idx / 80) % KP;
    int mat = idx / (80 * KP);
    const float* Wsrc = (mat < NL) ? (W1 + (size_t)mat * D * D) : (W2 + (size_t)(mat - NL) * D * D);
    float4 w = make_float4(0.f, 0.f, 0.f, 0.f);
    if (k < D && n4 < 75) w = *(const float4*)(Wsrc + (size_t)k * D + n4 * 4);
    size_t base = ((size_t)mat * 320 + n4 * 4) * KP + k;
    Wt[base]          = (u16)f2bf(w.x);
    Wt[base + KP]     = (u16)f2bf(w.y);
    Wt[base + 2 * KP] = (u16)f2bf(w.z);
    Wt[base + 3 * KP] = (u16)f2bf(w.w);
}

// ---------------------------------------------------------------------------
// x convert: xbf[row][c] = bf16(x[row][c]), pads (c>=300, row>=N) zero
// ---------------------------------------------------------------------------
__global__ __launch_bounds__(256)
void xcvt_kernel(const float* __restrict__ x, u16* __restrict__ xbf, int N) {
    int idx = blockIdx.x * 256 + threadIdx.x;
    if (idx >= NPAD * 40) return;
    int row = idx / 40;
    int c8 = (idx - row * 40) * 8;
    short o[8];
    #pragma unroll
    for (int i = 0; i < 8; ++i) {
        int c = c8 + i;
        float f = (row < N && c < D) ? x[(size_t)row * D + c] : 0.f;
        o[i] = f2bf(f);
    }
    *(bf16x8*)(xbf + (size_t)row * KP + c8) = *(bf16x8*)o;
}

// ---------------------------------------------------------------------------
// gather with fused BN2+ReLU on source rows; edge loop unrolled x2.
// ---------------------------------------------------------------------------
template<bool APPLY>
__global__ __launch_bounds__(256)
void gather_kernel(const u16* __restrict__ H, u16* __restrict__ Z,
                   const int* __restrict__ rowptr, const int* __restrict__ col,
                   const float* __restrict__ scsh, int N) {
    int idx = blockIdx.x * 256 + threadIdx.x;
    if (idx >= N * 40) return;
    int node = idx / 40;
    int c8 = (idx - node * 40) * 8;
    float sc[8], sh[8];
    if (APPLY) {
        #pragma unroll
        for (int i = 0; i < 8; ++i) { sc[i] = scsh[c8 + i]; sh[i] = scsh[KP + c8 + i]; }
    }
    int s = rowptr[node], e = rowptr[node + 1];
    bf16x8 v = *(const bf16x8*)(H + (size_t)node * KP + c8);
    float acc[8];
    #pragma unroll
    for (int i = 0; i < 8; ++i) {
        float f = bf2f(v[i]);
        acc[i] = APPLY ? fmaxf(fmaf(f, sc[i], sh[i]), 0.f) : f;
    }
    int j = s;
    for (; j + 2 <= e; j += 2) {           // 2 row-loads in flight
        int s0 = col[j], s1 = col[j + 1];
        bf16x8 w0 = *(const bf16x8*)(H + (size_t)s0 * KP + c8);
        bf16x8 w1 = *(const bf16x8*)(H + (size_t)s1 * KP + c8);
        #pragma unroll
        for (int i = 0; i < 8; ++i) {
            float f0 = bf2f(w0[i]);
            float f1 = bf2f(w1[i]);
            acc[i] += APPLY ? fmaxf(fmaf(f0, sc[i], sh[i]), 0.f) : f0;
            acc[i] += APPLY ? fmaxf(fmaf(f1, sc[i], sh[i]), 0.f) : f1;
        }
    }
    if (j < e) {
        int s0 = col[j];
        bf16x8 w0 = *(const bf16x8*)(H + (size_t)s0 * KP + c8);
        #pragma unroll
        for (int i = 0; i < 8; ++i) {
            float f0 = bf2f(w0[i]);
            acc[i] += APPLY ? fmaxf(fmaf(f0, sc[i], sh[i]), 0.f) : f0;
        }
    }
    short o[8];
    #pragma unroll
    for (int i = 0; i < 8; ++i) o[i] = f2bf(acc[i]);
    *(bf16x8*)(Z + (size_t)node * KP + c8) = *(bf16x8*)o;
}

// ---------------------------------------------------------------------------
// pool with optional fused BN2+ReLU; one block per graph, coalesced rows.
// ---------------------------------------------------------------------------
template<bool APPLY>
__global__ __launch_bounds__(320)
void pool_kernel(const u16* __restrict__ H, const int* __restrict__ off,
                 const float* __restrict__ scsh, float* __restrict__ pooled_l) {
    __shared__ float red[8][KP];
    int t = threadIdx.x;
    int g = blockIdx.x;
    int rq = t / 40;
    int c8 = (t - rq * 40) * 8;
    float sc[8], sh[8];
    if (APPLY) {
        #pragma unroll
        for (int i = 0; i < 8; ++i) { sc[i] = scsh[c8 + i]; sh[i] = scsh[KP + c8 + i]; }
    }
    int r0 = off[g], r1 = off[g + 1];
    float a[8] = {};
    for (int r = r0 + rq; r < r1; r += 8) {
        bf16x8 v = *(const bf16x8*)(H + (size_t)r * KP + c8);
        #pragma unroll
        for (int i = 0; i < 8; ++i) {
            float f = bf2f(v[i]);
            a[i] += APPLY ? fmaxf(fmaf(f, sc[i], sh[i]), 0.f) : f;
        }
    }
    #pragma unroll
    for (int i = 0; i < 8; ++i) red[rq][c8 + i] = a[i];
    __syncthreads();
    int c = t;
    if (c < D) {
        float s = 0.f;
        #pragma unroll
        for (int j = 0; j < 8; ++j) s += red[j][c];
        pooled_l[g * D + c] = s;
    }
}

// ---------------------------------------------------------------------------
// MFMA GEMM v5: one 64-row tile per block, col-HALVES (y in {0,1}).
//   - R3 post-mortem: __syncthreads drains vmcnt -> intra-block dbuf gave
//     ZERO overlap (stage serialized after compute, 93us). v5 deletes the
//     intra-block pipeline entirely: 1 tile/block, single 40KB buffer,
//     plain __syncthreads. Overlap comes from 2 INDEPENDENT blocks/CU:
//     block A's stage-wait runs under block B's compute. 1564 fine-grained
//     blocks also fix the v4 tail imbalance.
//   - col-halves: wave holds W for 2 col-groups in regs (80 VGPR); each A
//     ds_read_b128 feeds 4 MFMAs; A staged traffic 125MB -> 63MB.
//   - bias DELETED: every consumer of C sees it only through BN, which is
//     shift-invariant (mu absorbs b, var unchanged, shift be-mu*s
//     compensates). C now stores z-without-bias; bnfin output identical.
//   - stats: in-reg sum over rg, red16 over l16, lane15 global atomics.
//   - XOR swizzle (verified 0 conflicts in R3) kept on stage src + read.
// ---------------------------------------------------------------------------
template<bool APPLY>
__global__ __launch_bounds__(320, 3)
void mfma_gemm_kernel(const u16* __restrict__ Abf, const u16* __restrict__ Wt,
                      const float* __restrict__ scsh,
                      u16* __restrict__ Cbf, float* __restrict__ stats, int Nreal) {
    __shared__ u16 Ab[64 * 320];            // 40 KB
    const int tid  = threadIdx.x;
    const int wave = tid >> 6, lane = tid & 63;
    const int quad = lane >> 4, l16 = lane & 15;
    const int colb = blockIdx.y * 160;      // col half base
    const int tile = blockIdx.x;

    // ---- stage the 64x320 tile first (earliest HBM requests), swizzled src
    {
        const size_t rowb = (size_t)tile * 64;
        #pragma unroll
        for (int i = 0; i < 8; ++i) {
            int chunk = i * 320 + tid;
            int r  = chunk / 40;
            int cc = chunk - r * 40;
            int off = (cc * 16) ^ ((r & 7) << 4);      // swizzled byte off in row
            gload_lds16(Abf + (rowb + r) * KP + (off >> 1), &Ab[chunk * 8]);
        }
    }

    // ---- W fragments -> registers: 2 col-groups of 16 per wave
    bf16x8 bw[2][10];
    #pragma unroll
    for (int c = 0; c < 2; ++c) {
        const u16* wp = Wt + (size_t)(colb + c * 80 + wave * 16 + l16) * KP + quad * 8;
        #pragma unroll
        for (int kc = 0; kc < 10; ++kc) bw[c][kc] = *(const bf16x8*)(wp + kc * 32);
    }

    // scsh for the repack: this thread's fixed logical k-chunk
    float rsc[8], rsh[8];
    if (APPLY) {
        const int k0 = ((tid % 40) ^ ((tid / 40) & 7)) * 8;
        #pragma unroll
        for (int i = 0; i < 8; ++i) { rsc[i] = scsh[k0 + i]; rsh[i] = scsh[KP + k0 + i]; }
    }

    __syncthreads();                        // stage + W loads complete

    if (APPLY) {
        // repack staged tile in place: h = relu(z*sc + sh)
        #pragma unroll
        for (int u = 0; u < 8; ++u) {
            const int chunk = u * 320 + tid;
            bf16x8 v = *(const bf16x8*)&Ab[chunk * 8];
            float f[8];
            #pragma unroll
            for (int j = 0; j < 8; ++j)
                f[j] = fmaxf(fmaf(bf2f(v[j]), rsc[j], rsh[j]), 0.f);
            union { unsigned w[4]; bf16x8 v; } o;
            o.w[0] = cvtpk(f[0], f[1]);
            o.w[1] = cvtpk(f[2], f[3]);
            o.w[2] = cvtpk(f[4], f[5]);
            o.w[3] = cvtpk(f[6], f[7]);
            *(bf16x8*)&Ab[chunk * 8] = o.v;
        }
        __syncthreads();
    }

    // ---- MFMA: 10 kc x 4 rg ds_reads, each feeding 2 col-group MFMAs
    f32x4 acc[2][4] = {};
    #pragma unroll
    for (int kc = 0; kc < 10; ++kc) {
        #pragma unroll
        for (int rg = 0; rg < 4; ++rg) {
            const int row = rg * 16 + l16;
            const int off = (kc * 64 + quad * 16) ^ ((l16 & 7) << 4);
            bf16x8 af = *(const bf16x8*)&Ab[row * 320 + (off >> 1)];
            acc[0][rg] = __builtin_amdgcn_mfma_f32_16x16x32_bf16(bw[0][kc], af, acc[0][rg], 0, 0, 0);
            acc[1][rg] = __builtin_amdgcn_mfma_f32_16x16x32_bf16(bw[1][kc], af, acc[1][rg], 0, 0, 0);
        }
    }

    // ---- epilogue: store C (no bias) + column stats
    const int rowg = tile * 64 + l16;
    #pragma unroll
    for (int c = 0; c < 2; ++c) {
        u16* cr = Cbf + (size_t)rowg * KP + colb + c * 80 + wave * 16 + quad * 4;
        float s[4] = {0.f, 0.f, 0.f, 0.f}, q[4] = {0.f, 0.f, 0.f, 0.f};
        #pragma unroll
        for (int rg = 0; rg < 4; ++rg) {
            const bool ok = (rowg + rg * 16) < Nreal;
            float v0 = acc[c][rg][0], v1 = acc[c][rg][1];
            float v2 = acc[c][rg][2], v3 = acc[c][rg][3];
            uint2 w;
            w.x = cvtpk(v0, v1);
            w.y = cvtpk(v2, v3);
            *(uint2*)(cr + (size_t)(rg * 16) * KP) = w;
            float m0 = ok ? v0 : 0.f, m1 = ok ? v1 : 0.f;
            float m2 = ok ? v2 : 0.f, m3 = ok ? v3 : 0.f;
            s[0] += m0; s[1] += m1; s[2] += m2; s[3] += m3;
            q[0] = fmaf(m0, m0, q[0]); q[1] = fmaf(m1, m1, q[1]);
            q[2] = fmaf(m2, m2, q[2]); q[3] = fmaf(m3, m3, q[3]);
        }
        #pragma unroll
        for (int r = 0; r < 4; ++r) {
            float sv = red16(s[r]);
            float qv = red16(q[r]);
            if (l16 == 15) {
                int colg = colb + c * 80 + wave * 16 + quad * 4 + r;
                if (colg < D) {
                    atomAdd(&stats[colg], sv);
                    atomAdd(&stats[KP + colg], qv);
                }
            }
        }
    }
}

// ---------------------------------------------------------------------------
// BN finalize; self-zeroes stats for the next GEMM
// ---------------------------------------------------------------------------
__global__ void bnfin_kernel(float* __restrict__ sums, const float* __restrict__ g,
                             const float* __restrict__ be, float* __restrict__ scsh, float invN) {
    int c = threadIdx.x;
    if (c >= D) return;
    float mu = sums[c] * invN;
    float var = sums[KP + c] * invN - mu * mu;
    float s = g[c] / sqrtf(var + BN_EPS);
    scsh[c] = s;
    scsh[KP + c] = fmaf(-mu, s, be[c]);
    sums[c] = 0.f;
    sums[KP + c] = 0.f;
}

// ---------------------------------------------------------------------------
// readout
// ---------------------------------------------------------------------------
__global__ __launch_bounds__(128)
void bias_init_kernel(const float* __restrict__ fcb, float* __restrict__ out) {
    int i = blockIdx.x * 128 + threadIdx.x;
    if (i >= NGR * NC) return;
    int c = i & (NC - 1);
    float s = 0.f;
    for (int l = 0; l <= NL; ++l) s += fcb[l * NC + c];
    out[i] = s;
}

__global__ __launch_bounds__(128)
void readout_kernel(const float* __restrict__ pooled, const int* __restrict__ off,
                    const float* __restrict__ fcW, float* __restrict__ out) {
    __shared__ float sp[4][D];
    int c = threadIdx.x;
    int l = blockIdx.y;
    int g0 = blockIdx.x * 4;
    for (int i = c; i < 4 * D; i += 128) {
        int gg = i / D, k = i - gg * D;
        sp[gg][k] = pooled[((size_t)l * NGR + g0 + gg) * D + k];
    }
    __syncthreads();
    float acc[4] = {0.f, 0.f, 0.f, 0.f};
    for (int k = 0; k < D; ++k) {
        float w = fcW[((size_t)l * D + k) * NC + c];
        #pragma unroll
        for (int gg = 0; gg < 4; ++gg) acc[gg] = fmaf(sp[gg][k], w, acc[gg]);
    }
    #pragma unroll
    for (int gg = 0; gg < 4; ++gg) {
        int g = g0 + gg;
        float inv = 1.0f / fmaxf((float)(off[g + 1] - off[g]), 1.0f);
        atomAdd(&out[g * NC + c], acc[gg] * inv);
    }
}

// ---------------------------------------------------------------------------
extern "C" void kernel_launch(void* const* d_in, const int* in_sizes, int n_in,
                              void* d_out, int out_size, void* d_ws, size_t ws_size,
                              hipStream_t stream) {
    const float* x       = (const float*)d_in[0];
    const int*   ei      = (const int*)d_in[1];
    const int*   batch   = (const int*)d_in[2];
    const float* W1  = (const float*)d_in[3];
    const float* g1  = (const float*)d_in[5];
    const float* be1 = (const float*)d_in[6];
    const float* W2  = (const float*)d_in[7];
    const float* bng = (const float*)d_in[9];
    const float* bnb = (const float*)d_in[10];
    const float* fcW = (const float*)d_in[11];
    const float* fcb = (const float*)d_in[12];
    float* out = (float*)d_out;

    const int N = in_sizes[0] / D;   // 50000
    const int E = in_sizes[1] / 2;   // 400000
    const int nb = (N + 255) / 256;  // scan blocks

    u16* xbf  = (u16*)d_ws;                      // NPAD*KP
    u16* bufA = xbf + (size_t)NPAD * KP;         // NPAD*KP
    u16* bufB = bufA + (size_t)NPAD * KP;        // NPAD*KP
    u16* Wt   = bufB + (size_t)NPAD * KP;        // 10*320*KP
    float* pooled = (float*)(Wt + (size_t)10 * 320 * KP);    // 6*NGR*D
    float* stats  = pooled + (size_t)(NL + 1) * NGR * D;     // 2*KP
    float* sc1    = stats + 2 * KP;                          // 2*KP
    float* sc2    = sc1 + 2 * KP;                            // 2*KP
    int*   off    = (int*)(sc2 + 2 * KP);                    // NGR+1
    int*   rowptr = off + NGR + 1;                           // N+1
    int*   cursor = rowptr + N + 1;                          // N
    int*   col    = cursor + N;                              // E
    int*   part   = col + E;                                 // 256

    hipMemsetAsync(stats, 0, 6 * KP * sizeof(float), stream);   // stats + sc1 + sc2 pads
    offsets_kernel<<<1, 320, 0, stream>>>(batch, off, N);
    bias_init_kernel<<<(NGR * NC + 127) / 128, 128, 0, stream>>>(fcb, out);

    // ---- CSR build (once) ----
    hipMemsetAsync(cursor, 0, N * sizeof(int), stream);
    deg_kernel<<<(E + 255) / 256, 256, 0, stream>>>(ei, cursor, E);
    degpart_kernel<<<nb, 256, 0, stream>>>(cursor, part, N);
    partscan_kernel<<<1, 256, 0, stream>>>(part, nb);
    rowptr_kernel<<<nb, 256, 0, stream>>>(cursor, part, rowptr, N, E);
    hipMemsetAsync(cursor, 0, N * sizeof(int), stream);
    fill_kernel<<<(E + 255) / 256, 256, 0, stream>>>(ei, rowptr, cursor, col, E);

    // ---- precompute bf16 weights + input ----
    wcvt_kernel<<<(10 * KP * 80 + 255) / 256, 256, 0, stream>>>(W1, W2, Wt);
    xcvt_kernel<<<(NPAD * 40 + 255) / 256, 256, 0, stream>>>(x, xbf, N);

    const dim3 gemm_grid(NT64, 2);
    const int nd40 = N * 40;
    float invN = 1.0f / (float)N;
    const size_t WtM = (size_t)320 * KP;

    // pooled[0] = sum of raw x rows per graph
    pool_kernel<false><<<NGR, 320, 0, stream>>>(xbf, off, sc2, pooled);

    u16* g = bufA;
    u16* t = bufB;
    const u16* src = xbf;
    for (int l = 0; l < NL; ++l) {
        // gather (+BN2/ReLU of prev layer for l>0): src -> g
        if (l == 0)
            gather_kernel<false><<<(nd40 + 255) / 256, 256, 0, stream>>>(src, g, rowptr, col, sc2, N);
        else
            gather_kernel<true><<<(nd40 + 255) / 256, 256, 0, stream>>>(src, g, rowptr, col, sc2, N);
        // GEMM1 (+stats): g @ W1 -> t   (bias folded into BN; stats zeroed by prior bnfin)
        mfma_gemm_kernel<false><<<gemm_grid, 320, 0, stream>>>(
            g, Wt + (size_t)l * WtM, sc1, t, stats, N);
        bnfin_kernel<<<1, 320, 0, stream>>>(stats, g1 + l * D, be1 + l * D, sc1, invN);
        // GEMM2 (BN1+ReLU applied to staged A in LDS, +stats): t @ W2 -> g
        mfma_gemm_kernel<true><<<gemm_grid, 320, 0, stream>>>(
            t, Wt + (size_t)(NL + l) * WtM, sc1, g, stats, N);
        bnfin_kernel<<<1, 320, 0, stream>>>(stats, bng + l * D, bnb + l * D, sc2, invN);
        // pooled[l+1] = per-graph sum of relu(bn2(z_l)) via on-the-fly apply
        pool_kernel<true><<<NGR, 320, 0, stream>>>(g, off, sc2, pooled + (size_t)(l + 1) * NGR * D);
        src = g;
        u16* tmp = g; g = t; t = tmp;
    }
    readout_kernel<<<dim3(NGR / 4, NL + 1), 128, 0, stream>>>(pooled, off, fcW, out);
}

// Round 5
// 1007.482 us; speedup vs baseline: 1.9500x; 1.9500x over previous
//
#include <hip/hip_runtime.h>

#define D 300
#define KP 320
#define NPAD 50048
#define NT128 391       // NPAD/128 row-tiles of 128 (exact, no ragged tile)
#define WSTRIDE 328     // LDS k-stride (u16)
#define NGR 256
#define NL 5
#define NC 128
#define SPART 8         // stats atomic partitions
#define BN_EPS 1e-5f

typedef __attribute__((ext_vector_type(8))) short bf16x8;
typedef __attribute__((ext_vector_type(4))) float f32x4;
typedef unsigned short u16;

__device__ __forceinline__ void atomAdd(float* p, float v) { unsafeAtomicAdd(p, v); }

__device__ __forceinline__ short f2bf(float f) {
    union { float f; unsigned u; } v; v.f = f;
    unsigned r = v.u + 0x7fffu + ((v.u >> 16) & 1u);   // RNE
    return (short)(r >> 16);
}
__device__ __forceinline__ float bf2f(short s) {
    union { unsigned u; float f; } v;
    v.u = ((unsigned)(u16)s) << 16;
    return v.f;
}
// HW packed f32->bf16 (RNE), 1 instr per 2 values
__device__ __forceinline__ unsigned cvtpk(float lo, float hi) {
    unsigned r;
    asm("v_cvt_pk_bf16_f32 %0, %1, %2" : "=v"(r) : "v"(lo), "v"(hi));
    return r;
}
// DPP row_shr reduce over a 16-lane row: lane with (lane&15)==15 holds the sum.
template<int C>
__device__ __forceinline__ float rs_add(float v) {
    int x = __builtin_amdgcn_update_dpp(0, __float_as_int(v), C, 0xF, 0xF, true);
    return v + __int_as_float(x);
}
__device__ __forceinline__ float red16(float v) {
    v = rs_add<0x111>(v);   // row_shr:1
    v = rs_add<0x112>(v);   // row_shr:2
    v = rs_add<0x114>(v);   // row_shr:4
    v = rs_add<0x118>(v);   // row_shr:8
    return v;
}

// ---------------------------------------------------------------------------
// offsets: off[g] = lower_bound(batch, g)
// ---------------------------------------------------------------------------
__global__ void offsets_kernel(const int* __restrict__ batch, int* __restrict__ off, int N) {
    int g = threadIdx.x;
    if (g > NGR) return;
    int lo = 0, hi = N;
    while (lo < hi) {
        int mid = (lo + hi) >> 1;
        if (batch[mid] < g) lo = mid + 1; else hi = mid;
    }
    off[g] = lo;
}

// ---------------------------------------------------------------------------
// CSR build: deg histogram -> hierarchical scan -> slot fill
// ---------------------------------------------------------------------------
__global__ __launch_bounds__(256)
void deg_kernel(const int* __restrict__ ei, int* __restrict__ deg, int E) {
    int e = blockIdx.x * 256 + threadIdx.x;
    if (e < E) atomicAdd(&deg[ei[E + e]], 1);
}

__global__ __launch_bounds__(256)
void degpart_kernel(const int* __restrict__ deg, int* __restrict__ part, int N) {
    int i = blockIdx.x * 256 + threadIdx.x;
    int v = (i < N) ? deg[i] : 0;
    #pragma unroll
    for (int o = 1; o < 64; o <<= 1) v += __shfl_xor(v, o);
    __shared__ int ws[4];
    if ((threadIdx.x & 63) == 0) ws[threadIdx.x >> 6] = v;
    __syncthreads();
    if (threadIdx.x == 0) part[blockIdx.x] = ws[0] + ws[1] + ws[2] + ws[3];
}

__global__ __launch_bounds__(256)
void partscan_kernel(int* __restrict__ part, int nb) {   // 1 block; nb <= 256
    __shared__ int buf[256];
    int t = threadIdx.x;
    int v = (t < nb) ? part[t] : 0;
    buf[t] = v;
    __syncthreads();
    for (int o = 1; o < 256; o <<= 1) {
        int u = (t >= o) ? buf[t - o] : 0;
        __syncthreads();
        buf[t] += u;
        __syncthreads();
    }
    if (t < nb) part[t] = (t == 0) ? 0 : buf[t - 1];   // exclusive
}

__global__ __launch_bounds__(256)
void rowptr_kernel(const int* __restrict__ deg, const int* __restrict__ part,
                   int* __restrict__ rowptr, int N, int E) {
    __shared__ int buf[256];
    int b = blockIdx.x, t = threadIdx.x;
    int i = b * 256 + t;
    int v = (i < N) ? deg[i] : 0;
    buf[t] = v;
    __syncthreads();
    for (int o = 1; o < 256; o <<= 1) {
        int u = (t >= o) ? buf[t - o] : 0;
        __syncthreads();
        buf[t] += u;
        __syncthreads();
    }
    if (i < N) rowptr[i] = part[b] + buf[t] - v;
    if (b == 0 && t == 0) rowptr[N] = E;
}

__global__ __launch_bounds__(256)
void fill_kernel(const int* __restrict__ ei, const int* __restrict__ rowptr,
                 int* __restrict__ cursor, int* __restrict__ col, int E) {
    int e = blockIdx.x * 256 + threadIdx.x;
    if (e >= E) return;
    int src = ei[e];
    int dst = ei[E + e];
    int pos = atomicAdd(&cursor[dst], 1);
    col[rowptr[dst] + pos] = src;
}

// ---------------------------------------------------------------------------
// weight convert: Wt[mat][n (320)][k (320)] = bf16(W[k][n]); pads zero
// ---------------------------------------------------------------------------
__global__ __launch_bounds__(256)
void wcvt_kernel(const float* __restrict__ W1, const float* __restrict__ W2,
                 u16* __restrict__ Wt) {
    int idx = blockIdx.x * 256 + threadIdx.x;
    if (idx >= 10 * KP * 80) return;
    int n4 = idx % 80;
    int k = (idx / 80) % KP;
    int mat = idx / (80 * KP);
    const float* Wsrc = (mat < NL) ? (W1 + (size_t)mat * D * D) : (W2 + (size_t)(mat - NL) * D * D);
    float4 w = make_float4(0.f, 0.f, 0.f, 0.f);
    if (k < D && n4 < 75) w = *(const float4*)(Wsrc + (size_t)k * D + n4 * 4);
    size_t base = ((size_t)mat * 320 + n4 * 4) * KP + k;
    Wt[base]          = (u16)f2bf(w.x);
    Wt[base + KP]     = (u16)f2bf(w.y);
    Wt[base + 2 * KP] = (u16)f2bf(w.z);
    Wt[base + 3 * KP] = (u16)f2bf(w.w);
}

// ---------------------------------------------------------------------------
// x convert: xbf[row][c] = bf16(x[row][c]), pads (c>=300, row>=N) zero
// ---------------------------------------------------------------------------
__global__ __launch_bounds__(256)
void xcvt_kernel(const float* __restrict__ x, u16* __restrict__ xbf, int N) {
    int idx = blockIdx.x * 256 + threadIdx.x;
    if (idx >= NPAD * 40) return;
    int row = idx / 40;
    int c8 = (idx - row * 40) * 8;
    short o[8];
    #pragma unroll
    for (int i = 0; i < 8; ++i) {
        int c = c8 + i;
        float f = (row < N && c < D) ? x[(size_t)row * D + c] : 0.f;
        o[i] = f2bf(f);
    }
    *(bf16x8*)(xbf + (size_t)row * KP + c8) = *(bf16x8*)o;
}

// ---------------------------------------------------------------------------
// gather with fused BN2+ReLU on source rows; edge loop unrolled x2.
// ---------------------------------------------------------------------------
template<bool APPLY>
__global__ __launch_bounds__(256)
void gather_kernel(const u16* __restrict__ H, u16* __restrict__ Z,
                   const int* __restrict__ rowptr, const int* __restrict__ col,
                   const float* __restrict__ scsh, int N) {
    int idx = blockIdx.x * 256 + threadIdx.x;
    if (idx >= N * 40) return;
    int node = idx / 40;
    int c8 = (idx - node * 40) * 8;
    float sc[8], sh[8];
    if (APPLY) {
        #pragma unroll
        for (int i = 0; i < 8; ++i) { sc[i] = scsh[c8 + i]; sh[i] = scsh[KP + c8 + i]; }
    }
    int s = rowptr[node], e = rowptr[node + 1];
    bf16x8 v = *(const bf16x8*)(H + (size_t)node * KP + c8);
    float acc[8];
    #pragma unroll
    for (int i = 0; i < 8; ++i) {
        float f = bf2f(v[i]);
        acc[i] = APPLY ? fmaxf(fmaf(f, sc[i], sh[i]), 0.f) : f;
    }
    int j = s;
    for (; j + 2 <= e; j += 2) {           // 2 row-loads in flight
        int s0 = col[j], s1 = col[j + 1];
        bf16x8 w0 = *(const bf16x8*)(H + (size_t)s0 * KP + c8);
        bf16x8 w1 = *(const bf16x8*)(H + (size_t)s1 * KP + c8);
        #pragma unroll
        for (int i = 0; i < 8; ++i) {
            float f0 = bf2f(w0[i]);
            float f1 = bf2f(w1[i]);
            acc[i] += APPLY ? fmaxf(fmaf(f0, sc[i], sh[i]), 0.f) : f0;
            acc[i] += APPLY ? fmaxf(fmaf(f1, sc[i], sh[i]), 0.f) : f1;
        }
    }
    if (j < e) {
        int s0 = col[j];
        bf16x8 w0 = *(const bf16x8*)(H + (size_t)s0 * KP + c8);
        #pragma unroll
        for (int i = 0; i < 8; ++i) {
            float f0 = bf2f(w0[i]);
            acc[i] += APPLY ? fmaxf(fmaf(f0, sc[i], sh[i]), 0.f) : f0;
        }
    }
    short o[8];
    #pragma unroll
    for (int i = 0; i < 8; ++i) o[i] = f2bf(acc[i]);
    *(bf16x8*)(Z + (size_t)node * KP + c8) = *(bf16x8*)o;
}

// ---------------------------------------------------------------------------
// pool with optional fused BN2+ReLU; one block per graph, coalesced rows.
// ---------------------------------------------------------------------------
template<bool APPLY>
__global__ __launch_bounds__(320)
void pool_kernel(const u16* __restrict__ H, const int* __restrict__ off,
                 const float* __restrict__ scsh, float* __restrict__ pooled_l) {
    __shared__ float red[8][KP];
    int t = threadIdx.x;
    int g = blockIdx.x;
    int rq = t / 40;
    int c8 = (t - rq * 40) * 8;
    float sc[8], sh[8];
    if (APPLY) {
        #pragma unroll
        for (int i = 0; i < 8; ++i) { sc[i] = scsh[c8 + i]; sh[i] = scsh[KP + c8 + i]; }
    }
    int r0 = off[g], r1 = off[g + 1];
    float a[8] = {};
    for (int r = r0 + rq; r < r1; r += 8) {
        bf16x8 v = *(const bf16x8*)(H + (size_t)r * KP + c8);
        #pragma unroll
        for (int i = 0; i < 8; ++i) {
            float f = bf2f(v[i]);
            a[i] += APPLY ? fmaxf(fmaf(f, sc[i], sh[i]), 0.f) : f;
        }
    }
    #pragma unroll
    for (int i = 0; i < 8; ++i) red[rq][c8 + i] = a[i];
    __syncthreads();
    int c = t;
    if (c < D) {
        float s = 0.f;
        #pragma unroll
        for (int j = 0; j < 8; ++j) s += red[j][c];
        pooled_l[g * D + c] = s;
    }
}

// ---------------------------------------------------------------------------
// MFMA GEMM v6 = proven v3 skeleton (57us) with the diagnosed defect fixed:
//   - TPB=1: block = 128 rows x 80 cols, grid (391,4). ALL 20 per-thread
//     A-loads issue at block ENTRY, overlap the W-stage, and are consumed
//     immediately after the barrier -> no long live range to shrink.
//   - asm "+v" pins on every A fragment right before __syncthreads make
//     sinking past the barrier IMPOSSIBLE (R1/R2: compiler sank the
//     prefetch, VGPR stuck at 84, ~3KB/CU in flight). Barrier's vmcnt(0)
//     drain then guarantees 20KB/wave x 12 waves in flight during stage.
//   - stats: v3's hierarchical LDS lsum/lsq -> 160 global atomics/block,
//     now partitioned SPART ways by blockIdx.x (v5 lesson: 500K contended
//     device-scope atomics serialize); bnfin sums partitions.
//   - bias stays deleted (folded into BN shift; verified R4).
// ---------------------------------------------------------------------------
template<bool APPLY>
__global__ __launch_bounds__(256, 3)
void mfma_gemm_kernel(const u16* __restrict__ Abf, const u16* __restrict__ Wt,
                      const float* __restrict__ scsh,
                      u16* __restrict__ Cbf, float* __restrict__ stats, int Nreal) {
    __shared__ u16 Ws[80 * WSTRIDE];        // 52.5 KB
    __shared__ float lsum[80], lsq[80];
    const int tid = threadIdx.x;
    const int nBase = blockIdx.y * 80;
    const int wave = tid >> 6, lane = tid & 63;
    const int quad = lane >> 4, l16 = lane & 15;
    const int tile = blockIdx.x;

    // ---- A-loads FIRST (oldest in VMEM queue): wave covers rows
    //      tile*128 + wave*16 + l16 (+64)
    const u16* pA = Abf + (size_t)(tile * 128 + wave * 16 + l16) * KP + quad * 8;
    bf16x8 a[2][10];
    #pragma unroll
    for (int kc = 0; kc < 10; ++kc) {
        a[0][kc] = *(const bf16x8*)(pA + kc * 32);
        a[1][kc] = *(const bf16x8*)(pA + (size_t)64 * KP + kc * 32);
    }

    // ---- stage W quarter: 80 n-rows x 320 k, quad-slot XOR swizzle
    {
        const u16* src = Wt + (size_t)nBase * KP;
        for (int unit = tid; unit < 80 * 40; unit += 256) {
            int n = unit / 40, kg = unit - n * 40;
            int kc = kg >> 2, q = kg & 3;
            *(bf16x8*)&Ws[n * WSTRIDE + kc * 32 + ((q ^ (n & 3)) << 3)] =
                *(const bf16x8*)(src + (size_t)n * KP + kg * 8);
        }
    }
    if (tid < 80) { lsum[tid] = 0.f; lsq[tid] = 0.f; }

    // ---- pin A fragments: loads must complete-to-register HERE (barrier
    //      drains vmcnt anyway); compiler cannot sink them past the barrier.
    #pragma unroll
    for (int kc = 0; kc < 10; ++kc) {
        asm volatile("" : "+v"(a[0][kc]));
        asm volatile("" : "+v"(a[1][kc]));
    }
    __syncthreads();                        // barrier 1 of 2

    if (APPLY) {
        #pragma unroll
        for (int kc = 0; kc < 10; ++kc) {
            const float* sp = scsh + kc * 32 + quad * 8;
            float4 s0 = *(const float4*)sp;
            float4 s1 = *(const float4*)(sp + 4);
            float4 h0 = *(const float4*)(sp + KP);
            float4 h1 = *(const float4*)(sp + KP + 4);
            float sc[8] = {s0.x, s0.y, s0.z, s0.w, s1.x, s1.y, s1.z, s1.w};
            float sh[8] = {h0.x, h0.y, h0.z, h0.w, h1.x, h1.y, h1.z, h1.w};
            #pragma unroll
            for (int g = 0; g < 2; ++g) {
                float f[8];
                #pragma unroll
                for (int i = 0; i < 8; ++i)
                    f[i] = fmaxf(fmaf(bf2f(a[g][kc][i]), sc[i], sh[i]), 0.f);
                union { unsigned u[4]; bf16x8 v; } o;
                o.u[0] = cvtpk(f[0], f[1]);
                o.u[1] = cvtpk(f[2], f[3]);
                o.u[2] = cvtpk(f[4], f[5]);
                o.u[3] = cvtpk(f[6], f[7]);
                a[g][kc] = o.v;
            }
        }
    }

    // per-wave LDS read bases for the 5 n-subtiles (swizzled quad slot baked in)
    int wb[5];
    #pragma unroll
    for (int nt = 0; nt < 5; ++nt)
        wb[nt] = (nt * 16 + l16) * WSTRIDE + ((quad ^ (l16 & 3)) << 3);

    f32x4 acc[2][5] = {};
    __builtin_amdgcn_s_setprio(1);
    #pragma unroll
    for (int kc = 0; kc < 10; ++kc) {
        #pragma unroll
        for (int nt = 0; nt < 5; ++nt) {
            bf16x8 b = *(const bf16x8*)&Ws[wb[nt] + kc * 32];
            // swapped: D[n][m] = sum_k W[n][k] * A[m][k]
            acc[0][nt] = __builtin_amdgcn_mfma_f32_16x16x32_bf16(b, a[0][kc], acc[0][nt], 0, 0, 0);
            acc[1][nt] = __builtin_amdgcn_mfma_f32_16x16x32_bf16(b, a[1][kc], acc[1][nt], 0, 0, 0);
        }
    }
    __builtin_amdgcn_s_setprio(0);

    // ---- epilogue: thread owns rows {r0g, r0g+64}, cols quad*4..+3 per nt
    const int r0g = tile * 128 + wave * 16 + l16;
    const bool ok0 = r0g < Nreal, ok1 = (r0g + 64) < Nreal;
    u16* crow0 = Cbf + (size_t)r0g * KP + nBase + quad * 4;
    u16* crow1 = crow0 + (size_t)64 * KP;
    #pragma unroll
    for (int nt = 0; nt < 5; ++nt) {
        float v0[4], v1[4];
        #pragma unroll
        for (int r = 0; r < 4; ++r) { v0[r] = acc[0][nt][r]; v1[r] = acc[1][nt][r]; }
        uint2 w0, w1;
        w0.x = cvtpk(v0[0], v0[1]); w0.y = cvtpk(v0[2], v0[3]);
        w1.x = cvtpk(v1[0], v1[1]); w1.y = cvtpk(v1[2], v1[3]);
        *(uint2*)(crow0 + nt * 16) = w0;
        *(uint2*)(crow1 + nt * 16) = w1;
        #pragma unroll
        for (int r = 0; r < 4; ++r) {
            float s0 = ok0 ? v0[r] : 0.f;
            float s1 = ok1 ? v1[r] : 0.f;
            float sv = red16(s0 + s1);
            float qv = red16(fmaf(s0, s0, s1 * s1));
            if (l16 == 15) {
                atomicAdd(&lsum[nt * 16 + quad * 4 + r], sv);
                atomicAdd(&lsq [nt * 16 + quad * 4 + r], qv);
            }
        }
    }
    __syncthreads();                        // barrier 2 of 2
    if (tid < 80) {
        int colg = nBase + tid;
        if (colg < D) {
            float* sp = stats + (size_t)(blockIdx.x & (SPART - 1)) * 2 * KP;
            atomAdd(&sp[colg], lsum[tid]);
            atomAdd(&sp[KP + colg], lsq[tid]);
        }
    }
}

// ---------------------------------------------------------------------------
// BN finalize; sums SPART partitions, self-zeroes stats for the next GEMM
// ---------------------------------------------------------------------------
__global__ void bnfin_kernel(float* __restrict__ sums, const float* __restrict__ g,
                             const float* __restrict__ be, float* __restrict__ scsh, float invN) {
    int c = threadIdx.x;
    if (c >= D) return;
    float t1 = 0.f, t2 = 0.f;
    #pragma unroll
    for (int p = 0; p < SPART; ++p) {
        t1 += sums[(size_t)p * 2 * KP + c];
        t2 += sums[(size_t)p * 2 * KP + KP + c];
        sums[(size_t)p * 2 * KP + c] = 0.f;
        sums[(size_t)p * 2 * KP + KP + c] = 0.f;
    }
    float mu = t1 * invN;
    float var = t2 * invN - mu * mu;
    float s = g[c] / sqrtf(var + BN_EPS);
    scsh[c] = s;
    scsh[KP + c] = fmaf(-mu, s, be[c]);
}

// ---------------------------------------------------------------------------
// readout
// ---------------------------------------------------------------------------
__global__ __launch_bounds__(128)
void bias_init_kernel(const float* __restrict__ fcb, float* __restrict__ out) {
    int i = blockIdx.x * 128 + threadIdx.x;
    if (i >= NGR * NC) return;
    int c = i & (NC - 1);
    float s = 0.f;
    for (int l = 0; l <= NL; ++l) s += fcb[l * NC + c];
    out[i] = s;
}

__global__ __launch_bounds__(128)
void readout_kernel(const float* __restrict__ pooled, const int* __restrict__ off,
                    const float* __restrict__ fcW, float* __restrict__ out) {
    __shared__ float sp[4][D];
    int c = threadIdx.x;
    int l = blockIdx.y;
    int g0 = blockIdx.x * 4;
    for (int i = c; i < 4 * D; i += 128) {
        int gg = i / D, k = i - gg * D;
        sp[gg][k] = pooled[((size_t)l * NGR + g0 + gg) * D + k];
    }
    __syncthreads();
    float acc[4] = {0.f, 0.f, 0.f, 0.f};
    for (int k = 0; k < D; ++k) {
        float w = fcW[((size_t)l * D + k) * NC + c];
        #pragma unroll
        for (int gg = 0; gg < 4; ++gg) acc[gg] = fmaf(sp[gg][k], w, acc[gg]);
    }
    #pragma unroll
    for (int gg = 0; gg < 4; ++gg) {
        int g = g0 + gg;
        float inv = 1.0f / fmaxf((float)(off[g + 1] - off[g]), 1.0f);
        atomAdd(&out[g * NC + c], acc[gg] * inv);
    }
}

// ---------------------------------------------------------------------------
extern "C" void kernel_launch(void* const* d_in, const int* in_sizes, int n_in,
                              void* d_out, int out_size, void* d_ws, size_t ws_size,
                              hipStream_t stream) {
    const float* x       = (const float*)d_in[0];
    const int*   ei      = (const int*)d_in[1];
    const int*   batch   = (const int*)d_in[2];
    const float* W1  = (const float*)d_in[3];
    const float* g1  = (const float*)d_in[5];
    const float* be1 = (const float*)d_in[6];
    const float* W2  = (const float*)d_in[7];
    const float* bng = (const float*)d_in[9];
    const float* bnb = (const float*)d_in[10];
    const float* fcW = (const float*)d_in[11];
    const float* fcb = (const float*)d_in[12];
    float* out = (float*)d_out;

    const int N = in_sizes[0] / D;   // 50000
    const int E = in_sizes[1] / 2;   // 400000
    const int nb = (N + 255) / 256;  // scan blocks

    u16* xbf  = (u16*)d_ws;                      // NPAD*KP
    u16* bufA = xbf + (size_t)NPAD * KP;         // NPAD*KP
    u16* bufB = bufA + (size_t)NPAD * KP;        // NPAD*KP
    u16* Wt   = bufB + (size_t)NPAD * KP;        // 10*320*KP
    float* pooled = (float*)(Wt + (size_t)10 * 320 * KP);    // 6*NGR*D
    float* stats  = pooled + (size_t)(NL + 1) * NGR * D;     // SPART*2*KP
    float* sc1    = stats + (size_t)SPART * 2 * KP;          // 2*KP
    float* sc2    = sc1 + 2 * KP;                            // 2*KP
    int*   off    = (int*)(sc2 + 2 * KP);                    // NGR+1
    int*   rowptr = off + NGR + 1;                           // N+1
    int*   cursor = rowptr + N + 1;                          // N
    int*   col    = cursor + N;                              // E
    int*   part   = col + E;                                 // 256

    hipMemsetAsync(stats, 0, (SPART * 2 + 4) * KP * sizeof(float), stream); // stats + sc1 + sc2
    offsets_kernel<<<1, 320, 0, stream>>>(batch, off, N);
    bias_init_kernel<<<(NGR * NC + 127) / 128, 128, 0, stream>>>(fcb, out);

    // ---- CSR build (once) ----
    hipMemsetAsync(cursor, 0, N * sizeof(int), stream);
    deg_kernel<<<(E + 255) / 256, 256, 0, stream>>>(ei, cursor, E);
    degpart_kernel<<<nb, 256, 0, stream>>>(cursor, part, N);
    partscan_kernel<<<1, 256, 0, stream>>>(part, nb);
    rowptr_kernel<<<nb, 256, 0, stream>>>(cursor, part, rowptr, N, E);
    hipMemsetAsync(cursor, 0, N * sizeof(int), stream);
    fill_kernel<<<(E + 255) / 256, 256, 0, stream>>>(ei, rowptr, cursor, col, E);

    // ---- precompute bf16 weights + input ----
    wcvt_kernel<<<(10 * KP * 80 + 255) / 256, 256, 0, stream>>>(W1, W2, Wt);
    xcvt_kernel<<<(NPAD * 40 + 255) / 256, 256, 0, stream>>>(x, xbf, N);

    const dim3 gemm_grid(NT128, 4);
    const int nd40 = N * 40;
    float invN = 1.0f / (float)N;
    const size_t WtM = (size_t)320 * KP;

    // pooled[0] = sum of raw x rows per graph
    pool_kernel<false><<<NGR, 320, 0, stream>>>(xbf, off, sc2, pooled);

    u16* g = bufA;
    u16* t = bufB;
    const u16* src = xbf;
    for (int l = 0; l < NL; ++l) {
        // gather (+BN2/ReLU of prev layer for l>0): src -> g
        if (l == 0)
            gather_kernel<false><<<(nd40 + 255) / 256, 256, 0, stream>>>(src, g, rowptr, col, sc2, N);
        else
            gather_kernel<true><<<(nd40 + 255) / 256, 256, 0, stream>>>(src, g, rowptr, col, sc2, N);
        // GEMM1 (+stats): g @ W1 -> t   (bias folded into BN; stats zeroed by prior bnfin)
        mfma_gemm_kernel<false><<<gemm_grid, 256, 0, stream>>>(
            g, Wt + (size_t)l * WtM, sc1, t, stats, N);
        bnfin_kernel<<<1, 320, 0, stream>>>(stats, g1 + l * D, be1 + l * D, sc1, invN);
        // GEMM2 (BN1+ReLU on the fly, +stats): t @ W2 -> g   (z_l := g)
        mfma_gemm_kernel<true><<<gemm_grid, 256, 0, stream>>>(
            t, Wt + (size_t)(NL + l) * WtM, sc1, g, stats, N);
        bnfin_kernel<<<1, 320, 0, stream>>>(stats, bng + l * D, bnb + l * D, sc2, invN);
        // pooled[l+1] = per-graph sum of relu(bn2(z_l)) via on-the-fly apply
        pool_kernel<true><<<NGR, 320, 0, stream>>>(g, off, sc2, pooled + (size_t)(l + 1) * NGR * D);
        src = g;
        u16* tmp = g; g = t; t = tmp;
    }
    readout_kernel<<<dim3(NGR / 4, NL + 1), 128, 0, stream>>>(pooled, off, fcW, out);
}

// Round 6
// 938.233 us; speedup vs baseline: 2.0939x; 1.0738x over previous
//
#include <hip/hip_runtime.h>

#define D 300
#define KP 320
#define NPAD 50048
#define NT128 391       // NPAD/128 row-tiles of 128 (exact, no ragged tile)
#define WSTRIDE 328     // LDS k-stride (u16)
#define NGR 256
#define NL 5
#define NC 128
#define SPART 8         // stats atomic partitions
#define BN_EPS 1e-5f

typedef __attribute__((ext_vector_type(8))) short bf16x8;
typedef __attribute__((ext_vector_type(4))) float f32x4;
typedef unsigned short u16;

__device__ __forceinline__ void atomAdd(float* p, float v) { unsafeAtomicAdd(p, v); }

__device__ __forceinline__ short f2bf(float f) {
    union { float f; unsigned u; } v; v.f = f;
    unsigned r = v.u + 0x7fffu + ((v.u >> 16) & 1u);   // RNE
    return (short)(r >> 16);
}
__device__ __forceinline__ float bf2f(short s) {
    union { unsigned u; float f; } v;
    v.u = ((unsigned)(u16)s) << 16;
    return v.f;
}
// HW packed f32->bf16 (RNE), 1 instr per 2 values
__device__ __forceinline__ unsigned cvtpk(float lo, float hi) {
    unsigned r;
    asm("v_cvt_pk_bf16_f32 %0, %1, %2" : "=v"(r) : "v"(lo), "v"(hi));
    return r;
}
// DPP row_shr reduce over a 16-lane row: lane with (lane&15)==15 holds the sum.
template<int C>
__device__ __forceinline__ float rs_add(float v) {
    int x = __builtin_amdgcn_update_dpp(0, __float_as_int(v), C, 0xF, 0xF, true);
    return v + __int_as_float(x);
}
__device__ __forceinline__ float red16(float v) {
    v = rs_add<0x111>(v);   // row_shr:1
    v = rs_add<0x112>(v);   // row_shr:2
    v = rs_add<0x114>(v);   // row_shr:4
    v = rs_add<0x118>(v);   // row_shr:8
    return v;
}

// ---------------------------------------------------------------------------
// offsets: off[g] = lower_bound(batch, g)
// ---------------------------------------------------------------------------
__global__ void offsets_kernel(const int* __restrict__ batch, int* __restrict__ off, int N) {
    int g = threadIdx.x;
    if (g > NGR) return;
    int lo = 0, hi = N;
    while (lo < hi) {
        int mid = (lo + hi) >> 1;
        if (batch[mid] < g) lo = mid + 1; else hi = mid;
    }
    off[g] = lo;
}

// ---------------------------------------------------------------------------
// CSR build: deg histogram -> hierarchical scan -> slot fill
// ---------------------------------------------------------------------------
__global__ __launch_bounds__(256)
void deg_kernel(const int* __restrict__ ei, int* __restrict__ deg, int E) {
    int e = blockIdx.x * 256 + threadIdx.x;
    if (e < E) atomicAdd(&deg[ei[E + e]], 1);
}

__global__ __launch_bounds__(256)
void degpart_kernel(const int* __restrict__ deg, int* __restrict__ part, int N) {
    int i = blockIdx.x * 256 + threadIdx.x;
    int v = (i < N) ? deg[i] : 0;
    #pragma unroll
    for (int o = 1; o < 64; o <<= 1) v += __shfl_xor(v, o);
    __shared__ int ws[4];
    if ((threadIdx.x & 63) == 0) ws[threadIdx.x >> 6] = v;
    __syncthreads();
    if (threadIdx.x == 0) part[blockIdx.x] = ws[0] + ws[1] + ws[2] + ws[3];
}

__global__ __launch_bounds__(256)
void partscan_kernel(int* __restrict__ part, int nb) {   // 1 block; nb <= 256
    __shared__ int buf[256];
    int t = threadIdx.x;
    int v = (t < nb) ? part[t] : 0;
    buf[t] = v;
    __syncthreads();
    for (int o = 1; o < 256; o <<= 1) {
        int u = (t >= o) ? buf[t - o] : 0;
        __syncthreads();
        buf[t] += u;
        __syncthreads();
    }
    if (t < nb) part[t] = (t == 0) ? 0 : buf[t - 1];   // exclusive
}

__global__ __launch_bounds__(256)
void rowptr_kernel(const int* __restrict__ deg, const int* __restrict__ part,
                   int* __restrict__ rowptr, int N, int E) {
    __shared__ int buf[256];
    int b = blockIdx.x, t = threadIdx.x;
    int i = b * 256 + t;
    int v = (i < N) ? deg[i] : 0;
    buf[t] = v;
    __syncthreads();
    for (int o = 1; o < 256; o <<= 1) {
        int u = (t >= o) ? buf[t - o] : 0;
        __syncthreads();
        buf[t] += u;
        __syncthreads();
    }
    if (i < N) rowptr[i] = part[b] + buf[t] - v;
    if (b == 0 && t == 0) rowptr[N] = E;
}

__global__ __launch_bounds__(256)
void fill_kernel(const int* __restrict__ ei, const int* __restrict__ rowptr,
                 int* __restrict__ cursor, int* __restrict__ col, int E) {
    int e = blockIdx.x * 256 + threadIdx.x;
    if (e >= E) return;
    int src = ei[e];
    int dst = ei[E + e];
    int pos = atomicAdd(&cursor[dst], 1);
    col[rowptr[dst] + pos] = src;
}

// ---------------------------------------------------------------------------
// weight convert: Wt[mat][n (320)][k (320)] = bf16(W[k][n]); pads zero
// ---------------------------------------------------------------------------
__global__ __launch_bounds__(256)
void wcvt_kernel(const float* __restrict__ W1, const float* __restrict__ W2,
                 u16* __restrict__ Wt) {
    int idx = blockIdx.x * 256 + threadIdx.x;
    if (idx >= 10 * KP * 80) return;
    int n4 = idx % 80;
    int k = (idx / 80) % KP;
    int mat = idx / (80 * KP);
    const float* Wsrc = (mat < NL) ? (W1 + (size_t)mat * D * D) : (W2 + (size_t)(mat - NL) * D * D);
    float4 w = make_float4(0.f, 0.f, 0.f, 0.f);
    if (k < D && n4 < 75) w = *(const float4*)(Wsrc + (size_t)k * D + n4 * 4);
    size_t base = ((size_t)mat * 320 + n4 * 4) * KP + k;
    Wt[base]          = (u16)f2bf(w.x);
    Wt[base + KP]     = (u16)f2bf(w.y);
    Wt[base + 2 * KP] = (u16)f2bf(w.z);
    Wt[base + 3 * KP] = (u16)f2bf(w.w);
}

// ---------------------------------------------------------------------------
// x convert: xbf[row][c] = bf16(x[row][c]), pads (c>=300, row>=N) zero
// ---------------------------------------------------------------------------
__global__ __launch_bounds__(256)
void xcvt_kernel(const float* __restrict__ x, u16* __restrict__ xbf, int N) {
    int idx = blockIdx.x * 256 + threadIdx.x;
    if (idx >= NPAD * 40) return;
    int row = idx / 40;
    int c8 = (idx - row * 40) * 8;
    short o[8];
    #pragma unroll
    for (int i = 0; i < 8; ++i) {
        int c = c8 + i;
        float f = (row < N && c < D) ? x[(size_t)row * D + c] : 0.f;
        o[i] = f2bf(f);
    }
    *(bf16x8*)(xbf + (size_t)row * KP + c8) = *(bf16x8*)o;
}

// ---------------------------------------------------------------------------
// gather with fused BN2+ReLU on source rows; edge loop unrolled x2.
// ---------------------------------------------------------------------------
template<bool APPLY>
__global__ __launch_bounds__(256)
void gather_kernel(const u16* __restrict__ H, u16* __restrict__ Z,
                   const int* __restrict__ rowptr, const int* __restrict__ col,
                   const float* __restrict__ scsh, int N) {
    int idx = blockIdx.x * 256 + threadIdx.x;
    if (idx >= N * 40) return;
    int node = idx / 40;
    int c8 = (idx - node * 40) * 8;
    float sc[8], sh[8];
    if (APPLY) {
        #pragma unroll
        for (int i = 0; i < 8; ++i) { sc[i] = scsh[c8 + i]; sh[i] = scsh[KP + c8 + i]; }
    }
    int s = rowptr[node], e = rowptr[node + 1];
    bf16x8 v = *(const bf16x8*)(H + (size_t)node * KP + c8);
    float acc[8];
    #pragma unroll
    for (int i = 0; i < 8; ++i) {
        float f = bf2f(v[i]);
        acc[i] = APPLY ? fmaxf(fmaf(f, sc[i], sh[i]), 0.f) : f;
    }
    int j = s;
    for (; j + 2 <= e; j += 2) {           // 2 row-loads in flight
        int s0 = col[j], s1 = col[j + 1];
        bf16x8 w0 = *(const bf16x8*)(H + (size_t)s0 * KP + c8);
        bf16x8 w1 = *(const bf16x8*)(H + (size_t)s1 * KP + c8);
        #pragma unroll
        for (int i = 0; i < 8; ++i) {
            float f0 = bf2f(w0[i]);
            float f1 = bf2f(w1[i]);
            acc[i] += APPLY ? fmaxf(fmaf(f0, sc[i], sh[i]), 0.f) : f0;
            acc[i] += APPLY ? fmaxf(fmaf(f1, sc[i], sh[i]), 0.f) : f1;
        }
    }
    if (j < e) {
        int s0 = col[j];
        bf16x8 w0 = *(const bf16x8*)(H + (size_t)s0 * KP + c8);
        #pragma unroll
        for (int i = 0; i < 8; ++i) {
            float f0 = bf2f(w0[i]);
            acc[i] += APPLY ? fmaxf(fmaf(f0, sc[i], sh[i]), 0.f) : f0;
        }
    }
    short o[8];
    #pragma unroll
    for (int i = 0; i < 8; ++i) o[i] = f2bf(acc[i]);
    *(bf16x8*)(Z + (size_t)node * KP + c8) = *(bf16x8*)o;
}

// ---------------------------------------------------------------------------
// pool with optional fused BN2+ReLU; one block per graph, coalesced rows.
// ---------------------------------------------------------------------------
template<bool APPLY>
__global__ __launch_bounds__(320)
void pool_kernel(const u16* __restrict__ H, const int* __restrict__ off,
                 const float* __restrict__ scsh, float* __restrict__ pooled_l) {
    __shared__ float red[8][KP];
    int t = threadIdx.x;
    int g = blockIdx.x;
    int rq = t / 40;
    int c8 = (t - rq * 40) * 8;
    float sc[8], sh[8];
    if (APPLY) {
        #pragma unroll
        for (int i = 0; i < 8; ++i) { sc[i] = scsh[c8 + i]; sh[i] = scsh[KP + c8 + i]; }
    }
    int r0 = off[g], r1 = off[g + 1];
    float a[8] = {};
    for (int r = r0 + rq; r < r1; r += 8) {
        bf16x8 v = *(const bf16x8*)(H + (size_t)r * KP + c8);
        #pragma unroll
        for (int i = 0; i < 8; ++i) {
            float f = bf2f(v[i]);
            a[i] += APPLY ? fmaxf(fmaf(f, sc[i], sh[i]), 0.f) : f;
        }
    }
    #pragma unroll
    for (int i = 0; i < 8; ++i) red[rq][c8 + i] = a[i];
    __syncthreads();
    int c = t;
    if (c < D) {
        float s = 0.f;
        #pragma unroll
        for (int j = 0; j < 8; ++j) s += red[j][c];
        pooled_l[g * D + c] = s;
    }
}

// ---------------------------------------------------------------------------
// MFMA GEMM v7 = v6 (52us) + XCD-locality block remap:
//   R5 post-mortem: FETCH 63.7MB vs 32MB ideal A-read; the 4 col-quarter
//   blocks of a row-tile ran ~391 ids apart on DIFFERENT XCDs -> each
//   re-fetched A at ~900cy HBM latency. Remap (T1 mechanism, bid%8=XCD):
//     bid -> xcd = bid&7, pos = bid>>3, tile = xcd + (pos>>2)*8, q = pos&3
//   Quarters of a tile get bids 8 apart -> SAME XCD, temporally adjacent:
//   quarter 1 pulls the 80KB A-tile into that XCD's L2; quarters 2-4 hit
//   L2 (~200cy, 4.5x lower latency at the same in-flight bytes). W (205KB)
//   becomes L2-resident per XCD too. Bijective; 4 idle blocks (tile>=391).
// ---------------------------------------------------------------------------
template<bool APPLY>
__global__ __launch_bounds__(256, 3)
void mfma_gemm_kernel(const u16* __restrict__ Abf, const u16* __restrict__ Wt,
                      const float* __restrict__ scsh,
                      u16* __restrict__ Cbf, float* __restrict__ stats, int Nreal) {
    __shared__ u16 Ws[80 * WSTRIDE];        // 52.5 KB
    __shared__ float lsum[80], lsq[80];
    const int tid = threadIdx.x;
    const int bid = blockIdx.x;
    const int xcd = bid & 7;
    const int pos = bid >> 3;
    const int tile = xcd + ((pos >> 2) << 3);
    const int nBase = (pos & 3) * 80;
    if (tile >= NT128) return;              // uniform across block
    const int wave = tid >> 6, lane = tid & 63;
    const int quad = lane >> 4, l16 = lane & 15;

    // ---- A-loads FIRST (oldest in VMEM queue): wave covers rows
    //      tile*128 + wave*16 + l16 (+64)
    const u16* pA = Abf + (size_t)(tile * 128 + wave * 16 + l16) * KP + quad * 8;
    bf16x8 a[2][10];
    #pragma unroll
    for (int kc = 0; kc < 10; ++kc) {
        a[0][kc] = *(const bf16x8*)(pA + kc * 32);
        a[1][kc] = *(const bf16x8*)(pA + (size_t)64 * KP + kc * 32);
    }

    // ---- stage W quarter: 80 n-rows x 320 k, quad-slot XOR swizzle
    {
        const u16* src = Wt + (size_t)nBase * KP;
        for (int unit = tid; unit < 80 * 40; unit += 256) {
            int n = unit / 40, kg = unit - n * 40;
            int kc = kg >> 2, q = kg & 3;
            *(bf16x8*)&Ws[n * WSTRIDE + kc * 32 + ((q ^ (n & 3)) << 3)] =
                *(const bf16x8*)(src + (size_t)n * KP + kg * 8);
        }
    }
    if (tid < 80) { lsum[tid] = 0.f; lsq[tid] = 0.f; }

    // ---- pin A fragments before the barrier (barrier drains vmcnt anyway)
    #pragma unroll
    for (int kc = 0; kc < 10; ++kc) {
        asm volatile("" : "+v"(a[0][kc]));
        asm volatile("" : "+v"(a[1][kc]));
    }
    __syncthreads();                        // barrier 1 of 2

    if (APPLY) {
        #pragma unroll
        for (int kc = 0; kc < 10; ++kc) {
            const float* sp = scsh + kc * 32 + quad * 8;
            float4 s0 = *(const float4*)sp;
            float4 s1 = *(const float4*)(sp + 4);
            float4 h0 = *(const float4*)(sp + KP);
            float4 h1 = *(const float4*)(sp + KP + 4);
            float sc[8] = {s0.x, s0.y, s0.z, s0.w, s1.x, s1.y, s1.z, s1.w};
            float sh[8] = {h0.x, h0.y, h0.z, h0.w, h1.x, h1.y, h1.z, h1.w};
            #pragma unroll
            for (int g = 0; g < 2; ++g) {
                float f[8];
                #pragma unroll
                for (int i = 0; i < 8; ++i)
                    f[i] = fmaxf(fmaf(bf2f(a[g][kc][i]), sc[i], sh[i]), 0.f);
                union { unsigned u[4]; bf16x8 v; } o;
                o.u[0] = cvtpk(f[0], f[1]);
                o.u[1] = cvtpk(f[2], f[3]);
                o.u[2] = cvtpk(f[4], f[5]);
                o.u[3] = cvtpk(f[6], f[7]);
                a[g][kc] = o.v;
            }
        }
    }

    // per-wave LDS read bases for the 5 n-subtiles (swizzled quad slot baked in)
    int wb[5];
    #pragma unroll
    for (int nt = 0; nt < 5; ++nt)
        wb[nt] = (nt * 16 + l16) * WSTRIDE + ((quad ^ (l16 & 3)) << 3);

    f32x4 acc[2][5] = {};
    __builtin_amdgcn_s_setprio(1);
    #pragma unroll
    for (int kc = 0; kc < 10; ++kc) {
        #pragma unroll
        for (int nt = 0; nt < 5; ++nt) {
            bf16x8 b = *(const bf16x8*)&Ws[wb[nt] + kc * 32];
            // swapped: D[n][m] = sum_k W[n][k] * A[m][k]
            acc[0][nt] = __builtin_amdgcn_mfma_f32_16x16x32_bf16(b, a[0][kc], acc[0][nt], 0, 0, 0);
            acc[1][nt] = __builtin_amdgcn_mfma_f32_16x16x32_bf16(b, a[1][kc], acc[1][nt], 0, 0, 0);
        }
    }
    __builtin_amdgcn_s_setprio(0);

    // ---- epilogue: thread owns rows {r0g, r0g+64}, cols quad*4..+3 per nt
    const int r0g = tile * 128 + wave * 16 + l16;
    const bool ok0 = r0g < Nreal, ok1 = (r0g + 64) < Nreal;
    u16* crow0 = Cbf + (size_t)r0g * KP + nBase + quad * 4;
    u16* crow1 = crow0 + (size_t)64 * KP;
    #pragma unroll
    for (int nt = 0; nt < 5; ++nt) {
        float v0[4], v1[4];
        #pragma unroll
        for (int r = 0; r < 4; ++r) { v0[r] = acc[0][nt][r]; v1[r] = acc[1][nt][r]; }
        uint2 w0, w1;
        w0.x = cvtpk(v0[0], v0[1]); w0.y = cvtpk(v0[2], v0[3]);
        w1.x = cvtpk(v1[0], v1[1]); w1.y = cvtpk(v1[2], v1[3]);
        *(uint2*)(crow0 + nt * 16) = w0;
        *(uint2*)(crow1 + nt * 16) = w1;
        #pragma unroll
        for (int r = 0; r < 4; ++r) {
            float s0 = ok0 ? v0[r] : 0.f;
            float s1 = ok1 ? v1[r] : 0.f;
            float sv = red16(s0 + s1);
            float qv = red16(fmaf(s0, s0, s1 * s1));
            if (l16 == 15) {
                atomicAdd(&lsum[nt * 16 + quad * 4 + r], sv);
                atomicAdd(&lsq [nt * 16 + quad * 4 + r], qv);
            }
        }
    }
    __syncthreads();                        // barrier 2 of 2
    if (tid < 80) {
        int colg = nBase + tid;
        if (colg < D) {
            float* sp = stats + (size_t)(bid & (SPART - 1)) * 2 * KP;
            atomAdd(&sp[colg], lsum[tid]);
            atomAdd(&sp[KP + colg], lsq[tid]);
        }
    }
}

// ---------------------------------------------------------------------------
// BN finalize; sums SPART partitions, self-zeroes stats for the next GEMM
// ---------------------------------------------------------------------------
__global__ void bnfin_kernel(float* __restrict__ sums, const float* __restrict__ g,
                             const float* __restrict__ be, float* __restrict__ scsh, float invN) {
    int c = threadIdx.x;
    if (c >= D) return;
    float t1 = 0.f, t2 = 0.f;
    #pragma unroll
    for (int p = 0; p < SPART; ++p) {
        t1 += sums[(size_t)p * 2 * KP + c];
        t2 += sums[(size_t)p * 2 * KP + KP + c];
        sums[(size_t)p * 2 * KP + c] = 0.f;
        sums[(size_t)p * 2 * KP + KP + c] = 0.f;
    }
    float mu = t1 * invN;
    float var = t2 * invN - mu * mu;
    float s = g[c] / sqrtf(var + BN_EPS);
    scsh[c] = s;
    scsh[KP + c] = fmaf(-mu, s, be[c]);
}

// ---------------------------------------------------------------------------
// readout
// ---------------------------------------------------------------------------
__global__ __launch_bounds__(128)
void bias_init_kernel(const float* __restrict__ fcb, float* __restrict__ out) {
    int i = blockIdx.x * 128 + threadIdx.x;
    if (i >= NGR * NC) return;
    int c = i & (NC - 1);
    float s = 0.f;
    for (int l = 0; l <= NL; ++l) s += fcb[l * NC + c];
    out[i] = s;
}

__global__ __launch_bounds__(128)
void readout_kernel(const float* __restrict__ pooled, const int* __restrict__ off,
                    const float* __restrict__ fcW, float* __restrict__ out) {
    __shared__ float sp[4][D];
    int c = threadIdx.x;
    int l = blockIdx.y;
    int g0 = blockIdx.x * 4;
    for (int i = c; i < 4 * D; i += 128) {
        int gg = i / D, k = i - gg * D;
        sp[gg][k] = pooled[((size_t)l * NGR + g0 + gg) * D + k];
    }
    __syncthreads();
    float acc[4] = {0.f, 0.f, 0.f, 0.f};
    for (int k = 0; k < D; ++k) {
        float w = fcW[((size_t)l * D + k) * NC + c];
        #pragma unroll
        for (int gg = 0; gg < 4; ++gg) acc[gg] = fmaf(sp[gg][k], w, acc[gg]);
    }
    #pragma unroll
    for (int gg = 0; gg < 4; ++gg) {
        int g = g0 + gg;
        float inv = 1.0f / fmaxf((float)(off[g + 1] - off[g]), 1.0f);
        atomAdd(&out[g * NC + c], acc[gg] * inv);
    }
}

// ---------------------------------------------------------------------------
extern "C" void kernel_launch(void* const* d_in, const int* in_sizes, int n_in,
                              void* d_out, int out_size, void* d_ws, size_t ws_size,
                              hipStream_t stream) {
    const float* x       = (const float*)d_in[0];
    const int*   ei      = (const int*)d_in[1];
    const int*   batch   = (const int*)d_in[2];
    const float* W1  = (const float*)d_in[3];
    const float* g1  = (const float*)d_in[5];
    const float* be1 = (const float*)d_in[6];
    const float* W2  = (const float*)d_in[7];
    const float* bng = (const float*)d_in[9];
    const float* bnb = (const float*)d_in[10];
    const float* fcW = (const float*)d_in[11];
    const float* fcb = (const float*)d_in[12];
    float* out = (float*)d_out;

    const int N = in_sizes[0] / D;   // 50000
    const int E = in_sizes[1] / 2;   // 400000
    const int nb = (N + 255) / 256;  // scan blocks

    u16* xbf  = (u16*)d_ws;                      // NPAD*KP
    u16* bufA = xbf + (size_t)NPAD * KP;         // NPAD*KP
    u16* bufB = bufA + (size_t)NPAD * KP;        // NPAD*KP
    u16* Wt   = bufB + (size_t)NPAD * KP;        // 10*320*KP
    float* pooled = (float*)(Wt + (size_t)10 * 320 * KP);    // 6*NGR*D
    float* stats  = pooled + (size_t)(NL + 1) * NGR * D;     // SPART*2*KP
    float* sc1    = stats + (size_t)SPART * 2 * KP;          // 2*KP
    float* sc2    = sc1 + 2 * KP;                            // 2*KP
    int*   off    = (int*)(sc2 + 2 * KP);                    // NGR+1
    int*   rowptr = off + NGR + 1;                           // N+1
    int*   cursor = rowptr + N + 1;                          // N
    int*   col    = cursor + N;                              // E
    int*   part   = col + E;                                 // 256

    hipMemsetAsync(stats, 0, (SPART * 2 + 4) * KP * sizeof(float), stream); // stats + sc1 + sc2
    offsets_kernel<<<1, 320, 0, stream>>>(batch, off, N);
    bias_init_kernel<<<(NGR * NC + 127) / 128, 128, 0, stream>>>(fcb, out);

    // ---- CSR build (once) ----
    hipMemsetAsync(cursor, 0, N * sizeof(int), stream);
    deg_kernel<<<(E + 255) / 256, 256, 0, stream>>>(ei, cursor, E);
    degpart_kernel<<<nb, 256, 0, stream>>>(cursor, part, N);
    partscan_kernel<<<1, 256, 0, stream>>>(part, nb);
    rowptr_kernel<<<nb, 256, 0, stream>>>(cursor, part, rowptr, N, E);
    hipMemsetAsync(cursor, 0, N * sizeof(int), stream);
    fill_kernel<<<(E + 255) / 256, 256, 0, stream>>>(ei, rowptr, cursor, col, E);

    // ---- precompute bf16 weights + input ----
    wcvt_kernel<<<(10 * KP * 80 + 255) / 256, 256, 0, stream>>>(W1, W2, Wt);
    xcvt_kernel<<<(NPAD * 40 + 255) / 256, 256, 0, stream>>>(x, xbf, N);

    // grid: 8 XCD lanes x 49 tile-slots x 4 quarters (bijective remap inside)
    const int gemm_blocks = 8 * 49 * 4;   // 1568; 4 idle (tile>=391)
    const int nd40 = N * 40;
    float invN = 1.0f / (float)N;
    const size_t WtM = (size_t)320 * KP;

    // pooled[0] = sum of raw x rows per graph
    pool_kernel<false><<<NGR, 320, 0, stream>>>(xbf, off, sc2, pooled);

    u16* g = bufA;
    u16* t = bufB;
    const u16* src = xbf;
    for (int l = 0; l < NL; ++l) {
        // gather (+BN2/ReLU of prev layer for l>0): src -> g
        if (l == 0)
            gather_kernel<false><<<(nd40 + 255) / 256, 256, 0, stream>>>(src, g, rowptr, col, sc2, N);
        else
            gather_kernel<true><<<(nd40 + 255) / 256, 256, 0, stream>>>(src, g, rowptr, col, sc2, N);
        // GEMM1 (+stats): g @ W1 -> t   (bias folded into BN; stats zeroed by prior bnfin)
        mfma_gemm_kernel<false><<<gemm_blocks, 256, 0, stream>>>(
            g, Wt + (size_t)l * WtM, sc1, t, stats, N);
        bnfin_kernel<<<1, 320, 0, stream>>>(stats, g1 + l * D, be1 + l * D, sc1, invN);
        // GEMM2 (BN1+ReLU on the fly, +stats): t @ W2 -> g   (z_l := g)
        mfma_gemm_kernel<true><<<gemm_blocks, 256, 0, stream>>>(
            t, Wt + (size_t)(NL + l) * WtM, sc1, g, stats, N);
        bnfin_kernel<<<1, 320, 0, stream>>>(stats, bng + l * D, bnb + l * D, sc2, invN);
        // pooled[l+1] = per-graph sum of relu(bn2(z_l)) via on-the-fly apply
        pool_kernel<true><<<NGR, 320, 0, stream>>>(g, off, sc2, pooled + (size_t)(l + 1) * NGR * D);
        src = g;
        u16* tmp = g; g = t; t = tmp;
    }
    readout_kernel<<<dim3(NGR / 4, NL + 1), 128, 0, stream>>>(pooled, off, fcW, out);
}